// Round 3
// baseline (17671.455 us; speedup 1.0000x reference)
//
#include <hip/hip_runtime.h>

typedef unsigned short u16;
typedef __attribute__((ext_vector_type(8))) short bf16x8;   // 8 x bf16 (4 VGPRs)
typedef __attribute__((ext_vector_type(4))) float f32x4;

#define MFMA16(a, b, c) __builtin_amdgcn_mfma_f32_16x16x32_bf16((a), (b), (c), 0, 0, 0)

__device__ __forceinline__ u16 f2bf(float f) {
  union { float f; unsigned u; } v; v.f = f;
  unsigned r = v.u + 0x7FFF + ((v.u >> 16) & 1);   // round-to-nearest-even
  return (u16)(r >> 16);
}
__device__ __forceinline__ float bf2f(u16 h) {
  union { unsigned u; float f; } v; v.u = ((unsigned)h) << 16;
  return v.f;
}

// ---------- f32 -> bf16 bulk convert (n multiple of 8) ----------
__global__ void k_convert(const float* __restrict__ src, u16* __restrict__ dst, int n8) {
  int i = blockIdx.x * 256 + threadIdx.x;
  if (i >= n8) return;
  const float4* s = (const float4*)src + (size_t)i * 2;
  float4 a = s[0], b = s[1];
  u16 o[8] = { f2bf(a.x), f2bf(a.y), f2bf(a.z), f2bf(a.w),
               f2bf(b.x), f2bf(b.y), f2bf(b.z), f2bf(b.w) };
  *(bf16x8*)(dst + (size_t)i * 8) = *(bf16x8*)o;
}

// ---------- embedding gather -> A0 bf16, row i = t*64 + b ----------
__global__ void k_gather(const int* __restrict__ x, const float* __restrict__ emb,
                         u16* __restrict__ A0) {
  int gid = blockIdx.x * 256 + threadIdx.x;
  int row = gid >> 7;
  int e = (gid & 127) << 3;
  int t = row >> 6, b = row & 63;
  int v = x[b * 512 + t];
  const float4* s = (const float4*)(emb + (size_t)v * 1024 + e);
  float4 a = s[0], c = s[1];
  u16 o[8] = { f2bf(a.x), f2bf(a.y), f2bf(a.z), f2bf(a.w),
               f2bf(c.x), f2bf(c.y), f2bf(c.z), f2bf(c.w) };
  *(bf16x8*)(A0 + (size_t)row * 1024 + e) = *(bf16x8*)o;
}

// ---------- h0 init: f32 copy + bf16 copy (65536 elems) ----------
__global__ void k_hinit(const float* __restrict__ h0l, float* __restrict__ hf,
                        u16* __restrict__ hbf) {
  int i = blockIdx.x * 256 + threadIdx.x;
  float v = h0l[i];
  hf[i] = v;
  hbf[i] = f2bf(v);
}

// ---------- big GEMM: C[M=32768][3072] = A[M][1024] @ W[3072][1024]^T + bias ----------
__global__ __launch_bounds__(256) void k_gemm(const u16* __restrict__ A,
                                              const u16* __restrict__ W,
                                              const float* __restrict__ bias,
                                              u16* __restrict__ C) {
  __shared__ __attribute__((aligned(16))) u16 As[128 * 40];
  __shared__ __attribute__((aligned(16))) u16 Bs[128 * 40];
  int tid = threadIdx.x;
  int m0 = blockIdx.x * 128;
  int n0 = blockIdx.y * 128;
  int lane = tid & 63, wave = tid >> 6;
  int quad = lane >> 4, l15 = lane & 15;
  int wm = (wave >> 1) * 64, wn = (wave & 1) * 64;
  f32x4 acc[4][4] = {};
  for (int kc = 0; kc < 1024; kc += 32) {
#pragma unroll
    for (int i = 0; i < 2; i++) {
      int g = tid + i * 256;
      int row = g >> 2, kg = (g & 3) << 3;
      *(bf16x8*)(As + row * 40 + kg) = *(const bf16x8*)(A + (size_t)(m0 + row) * 1024 + kc + kg);
      *(bf16x8*)(Bs + row * 40 + kg) = *(const bf16x8*)(W + (size_t)(n0 + row) * 1024 + kc + kg);
    }
    __syncthreads();
    bf16x8 af[4], bf[4];
#pragma unroll
    for (int mi = 0; mi < 4; mi++)
      af[mi] = *(const bf16x8*)(As + (wm + mi * 16 + l15) * 40 + quad * 8);
#pragma unroll
    for (int ni = 0; ni < 4; ni++)
      bf[ni] = *(const bf16x8*)(Bs + (wn + ni * 16 + l15) * 40 + quad * 8);
#pragma unroll
    for (int mi = 0; mi < 4; mi++)
#pragma unroll
      for (int ni = 0; ni < 4; ni++)
        acc[mi][ni] = MFMA16(af[mi], bf[ni], acc[mi][ni]);
    __syncthreads();
  }
#pragma unroll
  for (int mi = 0; mi < 4; mi++)
#pragma unroll
    for (int ni = 0; ni < 4; ni++)
#pragma unroll
      for (int r = 0; r < 4; r++) {
        int m = m0 + wm + mi * 16 + quad * 4 + r;
        int n = n0 + wn + ni * 16 + l15;
        C[(size_t)m * 3072 + n] = f2bf(acc[mi][ni][r] + bias[n]);
      }
}

// ---------- two-level grid barrier (128 blocks = 8 groups x 16) ----------
// bar layout (uints): [0]=root cnt, [16]=generation, [32 + g*16]=group g cnt
__device__ __forceinline__ void grid_barrier(unsigned* bar) {
  __syncthreads();
  if (threadIdx.x == 0) {
    __threadfence();   // release: drain + make this block's writes device-visible
    unsigned g = __hip_atomic_load(bar + 16, __ATOMIC_RELAXED, __HIP_MEMORY_SCOPE_AGENT);
    int grp = blockIdx.x >> 4;
    unsigned a = __hip_atomic_fetch_add(bar + 32 + grp * 16, 1u, __ATOMIC_ACQ_REL,
                                        __HIP_MEMORY_SCOPE_AGENT);
    bool done = false;
    if (a == 15u) {
      __hip_atomic_store(bar + 32 + grp * 16, 0u, __ATOMIC_RELAXED, __HIP_MEMORY_SCOPE_AGENT);
      unsigned r = __hip_atomic_fetch_add(bar + 0, 1u, __ATOMIC_ACQ_REL,
                                          __HIP_MEMORY_SCOPE_AGENT);
      if (r == 7u) {
        __hip_atomic_store(bar + 0, 0u, __ATOMIC_RELAXED, __HIP_MEMORY_SCOPE_AGENT);
        __hip_atomic_store(bar + 16, g + 1u, __ATOMIC_RELEASE, __HIP_MEMORY_SCOPE_AGENT);
        done = true;
      }
    }
    if (!done) {
      // bounded spin: deadlock -> slow-fail with wrong output, not a hang
      for (unsigned it = 0; it < 4000000u; it++) {
        if (__hip_atomic_load(bar + 16, __ATOMIC_RELAXED, __HIP_MEMORY_SCOPE_AGENT) != g) break;
        __builtin_amdgcn_s_sleep(1);
      }
    }
    __threadfence();   // acquire: invalidate caches before re-reading h
  }
  __syncthreads();
}

// ---------- persistent GRU recurrence: 512 steps, Whh slice resident in LDS ----------
// 128 blocks x 256 threads; block = (jg = bid>>1 : 16 j-cols, mh = bid&1 : 32 batch rows).
// waves 0/1: gates r,z for M-tile (wave&1); waves 2/3: gate n, exchanged via LDS scratch.
__global__ __launch_bounds__(256, 1) void k_rnn(
    const u16* __restrict__ Whh, const float* __restrict__ bhh,
    const u16* __restrict__ gx,
    u16* __restrict__ hb0, u16* __restrict__ hb1,
    float* __restrict__ hf0, float* __restrict__ hf1,
    u16* __restrict__ A1,            // layer0: [t*64+m][1024] states out; else null
    float* __restrict__ hiddens,     // layer0: [b][t][1024] f32 out; else null
    float* __restrict__ hlast,       // final h [64][1024]
    float* __restrict__ outlast,     // layer1: out [64][1024]; else null
    unsigned* __restrict__ bar) {
  extern __shared__ __attribute__((aligned(16))) u16 lds[];
  u16* Whs = lds;                          // [48][1032] padded
  float* nscr = (float*)(lds + 48 * 1032); // [2][16][17]
  int tid = threadIdx.x;
  int lane = tid & 63, wave = tid >> 6;
  int quad = lane >> 4, l15 = lane & 15;
  int jg = blockIdx.x >> 1, mh = blockIdx.x & 1;
  int j0 = jg * 16;

  // stage Whh rows {gate*1024 + j0 + jr} once
  for (int idx = tid; idx < 48 * 128; idx += 256) {
    int row = idx >> 7, kg = (idx & 127) << 3;
    int gate = row >> 4, jr = row & 15;
    *(bf16x8*)(Whs + row * 1032 + kg) =
        *(const bf16x8*)(Whh + (size_t)(gate * 1024 + j0 + jr) * 1024 + kg);
  }
  __syncthreads();

  int mt = wave & 1;
  int m0 = mh * 32 + mt * 16;
  bool rz = (wave < 2);
  int j = j0 + l15;
  float br = bhh[j], bz = bhh[1024 + j], bn = bhh[2048 + j];
  const int arow = (m0 + l15) * 1024 + quad * 8;

  for (int t = 0; t < 512; t++) {
    const u16* hin; const float* hfin; u16* hout; float* hfout;
    if (t & 1) { hin = hb1; hfin = hf1; hout = hb0; hfout = hf0; }
    else       { hin = hb0; hfin = hf0; hout = hb1; hfout = hf1; }

    u16 xrv[4], xzv[4], xnv[4]; float hov[4];
    if (rz) {  // prefetch epilogue operands (HBM gx + f32 h) before the K-loop
      const u16* gxt = gx + (size_t)t * 196608;
#pragma unroll
      for (int r = 0; r < 4; r++) {
        int m = m0 + quad * 4 + r;
        xrv[r] = gxt[m * 3072 + j];
        xzv[r] = gxt[m * 3072 + 1024 + j];
        xnv[r] = gxt[m * 3072 + 2048 + j];
        hov[r] = hfin[m * 1024 + j];
      }
    }

    f32x4 acc0 = {}, acc1 = {};
    const u16* hrow = hin + arow;
    if (rz) {
#pragma unroll 8
      for (int kk = 0; kk < 1024; kk += 32) {
        bf16x8 a = *(const bf16x8*)(hrow + kk);
        bf16x8 b0 = *(const bf16x8*)(Whs + l15 * 1032 + kk + quad * 8);
        bf16x8 b1 = *(const bf16x8*)(Whs + (16 + l15) * 1032 + kk + quad * 8);
        acc0 = MFMA16(a, b0, acc0);
        acc1 = MFMA16(a, b1, acc1);
      }
    } else {
#pragma unroll 8
      for (int kk = 0; kk < 1024; kk += 32) {
        bf16x8 a = *(const bf16x8*)(hrow + kk);
        bf16x8 b = *(const bf16x8*)(Whs + (32 + l15) * 1032 + kk + quad * 8);
        acc0 = MFMA16(a, b, acc0);
      }
#pragma unroll
      for (int r = 0; r < 4; r++)
        nscr[mt * 272 + (quad * 4 + r) * 17 + l15] = acc0[r];
    }
    __syncthreads();

    if (rz) {
#pragma unroll
      for (int r = 0; r < 4; r++) {
        int m = m0 + quad * 4 + r;
        float nacc = nscr[mt * 272 + (quad * 4 + r) * 17 + l15];
        float rg = 1.f / (1.f + __expf(-(bf2f(xrv[r]) + acc0[r] + br)));
        float zg = 1.f / (1.f + __expf(-(bf2f(xzv[r]) + acc1[r] + bz)));
        float nx = bf2f(xnv[r]) + rg * (nacc + bn);
        nx = fminf(15.f, fmaxf(-15.f, nx));
        float e2 = __expf(2.f * nx);
        float ng = (e2 - 1.f) / (e2 + 1.f);
        float hnew = (1.f - zg) * ng + zg * hov[r];
        hfout[m * 1024 + j] = hnew;
        hout[m * 1024 + j] = f2bf(hnew);
        if (A1) A1[((size_t)t * 64 + m) * 1024 + j] = f2bf(hnew);
        if (hiddens) hiddens[(size_t)m * 524288 + (size_t)t * 1024 + j] = hnew;
        if (t == 511) {
          hlast[m * 1024 + j] = hnew;
          if (outlast) outlast[m * 1024 + j] = hnew;
        }
      }
    }
    grid_barrier(bar);
  }
}

extern "C" void kernel_launch(void* const* d_in, const int* in_sizes, int n_in,
                              void* d_out, int out_size, void* d_ws, size_t ws_size,
                              hipStream_t stream) {
  const int*   x   = (const int*)d_in[0];
  const float* h0  = (const float*)d_in[1];
  const float* emb = (const float*)d_in[2];
  const float* Wih = (const float*)d_in[3];
  const float* Whh = (const float*)d_in[4];
  const float* bih = (const float*)d_in[5];
  const float* bhh = (const float*)d_in[6];
  float* out = (float*)d_out;

  char* ws = (char*)d_ws;
  u16* WihB = (u16*)ws;  ws += 12582912;
  u16* WhhB = (u16*)ws;  ws += 12582912;
  u16* A0   = (u16*)ws;  ws += 67108864;
  u16* A1   = (u16*)ws;  ws += 67108864;
  u16* gx   = (u16*)ws;  ws += 201326592;
  u16* hb0  = (u16*)ws;  ws += 131072;
  u16* hb1  = (u16*)ws;  ws += 131072;
  float* hf0 = (float*)ws; ws += 262144;
  float* hf1 = (float*)ws; ws += 262144;
  unsigned* bar = (unsigned*)ws; ws += 1024;

  float* out_out = out;
  float* hidden0 = out + 65536;
  float* hidden1 = out + 131072;
  float* hiddens = out + 196608;

  const size_t WSTRIDE = 3145728;   // per-layer stride of [L][3072][1024]
  const size_t RNN_LDS = 48 * 1032 * 2 + 2 * 16 * 17 * 4;  // 101248 B

  hipMemsetAsync(bar, 0, 1024, stream);
  k_convert<<<3072, 256, 0, stream>>>(Wih, WihB, 786432);
  k_convert<<<3072, 256, 0, stream>>>(Whh, WhhB, 786432);
  k_gather<<<16384, 256, 0, stream>>>(x, emb, A0);
  k_hinit<<<256, 256, 0, stream>>>(h0, hf0, hb0);

  dim3 ggrid(256, 24);
  k_gemm<<<ggrid, 256, 0, stream>>>(A0, WihB, bih, gx);

  k_rnn<<<128, 256, RNN_LDS, stream>>>(WhhB, bhh, gx, hb0, hb1, hf0, hf1,
                                       A1, hiddens, hidden0, nullptr, bar);

  k_gemm<<<ggrid, 256, 0, stream>>>(A1, WihB + WSTRIDE, bih + 3072, gx);
  k_hinit<<<256, 256, 0, stream>>>(h0 + 65536, hf0, hb0);

  k_rnn<<<128, 256, RNN_LDS, stream>>>(WhhB + WSTRIDE, bhh + 3072, gx, hb0, hb1, hf0, hf1,
                                       nullptr, nullptr, hidden1, out_out, bar);
}